// Round 4
// baseline (314.594 us; speedup 1.0000x reference)
//
#include <hip/hip_runtime.h>
#include <hip/hip_bf16.h>

#define C_ 256
#define H_ 64
#define W_ 64
#define N_ 16
#define HW_ 4096
#define IMG_ (C_ * HW_)          // 1048576 elems (fp32 image)
#define PADIMG_ (66 * 66 * 256)  // 1115136 shorts per padded NHWC image
#define WT_ELEMS_ (9 * 16 * 256 * 16)

typedef short bf16x8 __attribute__((ext_vector_type(8)));
typedef float f32x16 __attribute__((ext_vector_type(16)));

__device__ __forceinline__ unsigned short f2bf(float f) {
  __hip_bfloat16 h = __float2bfloat16(f);  // RTNE
  return *reinterpret_cast<unsigned short*>(&h);
}

__device__ __forceinline__ void gld_lds16(const void* g, void* l) {
  __builtin_amdgcn_global_load_lds(
      (const __attribute__((address_space(1))) void*)g,
      (__attribute__((address_space(3))) void*)l, 16, 0, 0);
}

// ---------------------------------------------------------------------------
// Fused x->padded-NHWC-bf16 transform + mask logits (fp64, sign-exact).
// ---------------------------------------------------------------------------
__global__ __launch_bounds__(256) void xpadmask_kernel(
    const float* __restrict__ x, const float* __restrict__ wm,
    const float* __restrict__ bm, short* __restrict__ Xp,
    unsigned char* __restrict__ mask) {
  __shared__ unsigned short lds[64 * 260];
  __shared__ float wms[256];
  __shared__ double sums[4][64];
  const int h = blockIdx.x, img = blockIdx.y;
  const int tid = threadIdx.x;
  const int wv = tid >> 6, wl = tid & 63;
  wms[tid] = wm[tid];
  __syncthreads();
  const float* xi = x + (size_t)img * IMG_ + h * 64;
  double a0 = 0.0, a1 = 0.0, a2 = 0.0, a3 = 0.0;
#pragma unroll 4
  for (int i = 0; i < 16; ++i) {
#pragma unroll
    for (int u = 0; u < 4; ++u) {
      int c = (i * 4 + u) * 4 + wv;
      float v = xi[(size_t)c * HW_ + wl];
      lds[wl * 260 + c] = f2bf(v);
      double p = (double)v * (double)wms[c];
      if (u == 0) a0 += p;
      else if (u == 1) a1 += p;
      else if (u == 2) a2 += p;
      else a3 += p;
    }
  }
  sums[wv][wl] = (a0 + a1) + (a2 + a3);
  __syncthreads();
  short* Xpi = Xp + (size_t)img * PADIMG_ + ((h + 1) * 66 + 1) * 256;
#pragma unroll
  for (int j = 0; j < 16; ++j) {
    int w = j * 4 + wv;
    int c4 = wl * 4;
    uint2 d = *(const uint2*)&lds[w * 260 + c4];
    *(uint2*)&Xpi[(size_t)w * 256 + c4] = d;
  }
  if (wv == 0) {
    double t = sums[0][wl] + sums[1][wl] + sums[2][wl] + sums[3][wl] +
               (double)bm[0];
    mask[img * HW_ + h * 64 + wl] = (t > 0.0) ? 1 : 0;
  }
}

// ---------------------------------------------------------------------------
// Weight transform: Wt[t][kc][k][c16] = bf16(w[k][kc*16+c16][t])
// Layout so a conv wave's a-frag pair (64 lanes x 16B) is one contiguous,
// fully-coalesced 1KB global load.
// ---------------------------------------------------------------------------
__global__ __launch_bounds__(256) void wt_kernel(
    const float* __restrict__ w1, const float* __restrict__ w2,
    short* __restrict__ Wt1, short* __restrict__ Wt2) {
  const int k = blockIdx.x, c = threadIdx.x;
  const float* src = blockIdx.y ? w2 : w1;
  short* dst = blockIdx.y ? Wt2 : Wt1;
  const float* s = src + ((size_t)k * 256 + c) * 9;
  const int kc = c >> 4, ce = c & 15;
#pragma unroll
  for (int t = 0; t < 9; ++t)
    dst[(((size_t)t * 16 + kc) * 256 + k) * 16 + ce] = (short)f2bf(s[t]);
}

// ---------------------------------------------------------------------------
// Zero the padded halo (rows 0,65; cols 0,65) of Xp and Hp.
// ---------------------------------------------------------------------------
__global__ __launch_bounds__(128) void halo_zero(short* __restrict__ Xp,
                                                 short* __restrict__ Hp) {
  int p = blockIdx.x;  // 0..259 halo pixel id
  int r, c;
  if (p < 66) { r = 0; c = p; }
  else if (p < 132) { r = 65; c = p - 66; }
  else if (p < 196) { r = p - 131; c = 0; }
  else { r = p - 195; c = 65; }
  short* buf = blockIdx.z ? Hp : Xp;
  unsigned int* d = (unsigned int*)(buf + (size_t)blockIdx.y * PADIMG_ +
                                    (size_t)(r * 66 + c) * 256);
  d[threadIdx.x] = 0u;
}

// ---------------------------------------------------------------------------
// Implicit-GEMM 3x3 conv, v5 (occupancy: 4 waves/SIMD).
// Round-3 lesson: acc[2][4]=128 AGPR + 128 VGPR = 256 regs/wave capped the
// kernel at 2 waves/SIMD; deep source-level prefetch was then worthless (two
// flat rounds). This version halves per-wave state to double TLP:
//   block = 64 out-ch x 512 px (8 rows x 64 cols), 8 waves of 512 threads,
//   wave w owns out row h0+w (64 px): acc[2 ch][2 col] = 64 AGPR,
//   VGPR target 64 -> 128 regs/wave -> 4 waves/SIMD (2 indep blocks/CU).
// MFMA 32x32x16 bf16, K-chunk 16 (16 chunks), LDS 63360 B = 3 x 21120 B
// triple-buffered B tile (W via L2->regs, 1-tap double buffer).
// Pipeline unchanged from v3: stage B(kk+2) at end of kk; vmcnt-FIFO retires
// it via kk+1's early W-waits; boundary is a bare s_barrier (no drain).
// EPI 0: dstH[padded NHWC] = g ? relu(acc) : 0   (g = 3x3 OR of mask, fused
//        dilation)
// EPI 1: dstF[NCHW fp32]   = xres + (g ? relu(acc):0)   (g = std mask)
// ---------------------------------------------------------------------------
#define BBUF 10560  // shorts per B k-chunk buffer (2 K-halves x 660 x 8)

__device__ __forceinline__ void stage_B(short* sm, int buf, const short* Xb,
                                        int ko, int wave, int lane) {
  short* Bd = sm + buf * BBUF;
  // 22 insts (11 per K-half; inst i<10 covers slots 64i..64i+63, inst 10
  // covers 596..659 overlapping inst 9 with identical data). Waves 6,7 dup
  // inst 21 (same bytes -> benign) so all 8 waves issue 3 (vmcnt symmetric).
#pragma unroll
  for (int q = 0; q < 3; ++q) {
    int n = wave + 8 * q;
    if (n > 21) n = 21;
    const int h = (n >= 11) ? 1 : 0;
    const int i = n - h * 11;
    const int row0 = (i < 10) ? i * 64 : 596;
    gld_lds16(Xb + (size_t)(row0 + lane) * 256 + ko + h * 8,
              Bd + h * 5280 + row0 * 8);
  }
}

template <int EPI>
__global__ __launch_bounds__(512, 4) void conv_mfma(
    const short* __restrict__ src, const short* __restrict__ Wt,
    const unsigned char* __restrict__ gate, const float* __restrict__ xres,
    short* __restrict__ dstH, float* __restrict__ dstF, int swz) {
  __shared__ __align__(16) short sm[3 * BBUF];  // 63360 B -> 2 blocks/CU

  const int tid = threadIdx.x;
  const int lane = tid & 63, wave = tid >> 6;  // 8 waves
  const int ln31 = lane & 31, kh = lane >> 5;

  // Block decode; swizzled path groups the 4 ch-sibling blocks on one XCD.
  int bx, by, bz;
  {
    int d = blockIdx.x + 4 * (blockIdx.y + 8 * blockIdx.z);
    if (swz) {
      int k = d & 7, j = d >> 3;
      bx = j & 3;
      by = (j >> 2) & 7;
      bz = ((j >> 5) << 3) + k;
    } else {
      bx = blockIdx.x;
      by = blockIdx.y;
      bz = blockIdx.z;
    }
  }
  const int ch0 = bx * 64;
  const int h0 = by * 8;
  const int img = bz;

  const short* Xb = src + (size_t)img * PADIMG_ + (size_t)(h0 * 66) * 256;
  // Per-lane W base: element ((t*16+kc)*256 + ch0 + khalf-interleaved lane)
  const short* WL = Wt + ((size_t)(ch0 + ln31)) * 16 + kh * 8;

  f32x16 acc[2][2];
#pragma unroll
  for (int i = 0; i < 2; ++i)
#pragma unroll
    for (int j = 0; j < 2; ++j)
#pragma unroll
      for (int e = 0; e < 16; ++e) acc[i][j][e] = 0.f;

  // Prologue: B(0), B(1) staged (3 loads each/wave); W(0,t0) pair issued.
  stage_B(sm, 0, Xb, 0, wave, lane);
  stage_B(sm, 1, Xb, 16, wave, lane);
  bf16x8 wc0 = *(const bf16x8*)(WL);      // (t=0, kc=0)
  bf16x8 wc1 = *(const bf16x8*)(WL + 512);
  // vmcnt(2): the 6 stage loads retired; the 2 W loads may stay in flight.
  asm volatile("s_waitcnt vmcnt(2)\n\ts_barrier" ::: "memory");

  int c0 = 0, c1 = 1, c2 = 2;
  for (int kk = 0; kk < 16; ++kk) {
    // Wave w reads padded rows (w+dy), 66-slot pitch, cols j*32+dx.
    const short* Bth = sm + c0 * BBUF + kh * 5280 + (wave * 66 + ln31) * 8;
#pragma unroll
    for (int t = 0; t < 9; ++t) {
      // W prefetch for tap t+1 (t=8 -> (kk+1, tap0); kk=15 tail lands
      // in-bounds inside Wt's t=1 region and is never consumed).
      const int ntkc = (t < 8) ? ((t + 1) * 16 + kk) : (kk + 1);
      bf16x8 na0 = *(const bf16x8*)(WL + (size_t)ntkc * 4096);
      bf16x8 na1 = *(const bf16x8*)(WL + (size_t)ntkc * 4096 + 512);
      const int dy = t / 3, dx = t % 3;
      bf16x8 b[2];
#pragma unroll
      for (int j = 0; j < 2; ++j)
        b[j] = *(const bf16x8*)(Bth + (dy * 66 + j * 32 + dx) * 8);
      __builtin_amdgcn_s_setprio(1);
#pragma unroll
      for (int j = 0; j < 2; ++j) {
        acc[0][j] = __builtin_amdgcn_mfma_f32_32x32x16_bf16(wc0, b[j],
                                                            acc[0][j], 0, 0, 0);
        acc[1][j] = __builtin_amdgcn_mfma_f32_32x32x16_bf16(wc1, b[j],
                                                            acc[1][j], 0, 0, 0);
      }
      __builtin_amdgcn_s_setprio(0);
      wc0 = na0;
      wc1 = na1;
    }
    // Next-next B stage after this kk's W issues (vmcnt-FIFO keeps it in
    // flight across the boundary; retired by kk+1's early W-waits).
    if (kk < 14) stage_B(sm, c2, Xb, (kk + 2) * 16, wave, lane);
    if (kk < 15) asm volatile("s_barrier" ::: "memory");
    const int tmp = c0;
    c0 = c1;
    c1 = c2;
    c2 = tmp;
  }

  // Epilogue. 32x32 D layout: col(pixel)=lane&31, row(ch)=(reg&3)+8*(reg>>2)
  // +4*(lane>>5)  => reg group rg gives 4 consecutive channels.
  const int r = h0 + wave;
#pragma unroll
  for (int j = 0; j < 2; ++j) {
    const int col = j * 32 + ln31;
    const int pidx = r * 64 + col;
    unsigned int g;
    if (EPI == 0) {
      // fused dilation: 3x3 OR of std mask around (r,col)
      g = 0;
#pragma unroll
      for (int dy = -1; dy <= 1; ++dy) {
        const int rr = r + dy;
        if (rr < 0 || rr >= H_) continue;
#pragma unroll
        for (int dx = -1; dx <= 1; ++dx) {
          const int cc = col + dx;
          if (cc < 0 || cc >= W_) continue;
          g |= gate[img * HW_ + rr * W_ + cc];
        }
      }
    } else {
      g = gate[img * HW_ + pidx];
    }
#pragma unroll
    for (int i = 0; i < 2; ++i) {
      const f32x16 v = acc[i][j];
#pragma unroll
      for (int rg = 0; rg < 4; ++rg) {
        const int ch = ch0 + i * 32 + rg * 8 + kh * 4;
        float e0 = g ? fmaxf(v[rg * 4 + 0], 0.f) : 0.f;
        float e1 = g ? fmaxf(v[rg * 4 + 1], 0.f) : 0.f;
        float e2 = g ? fmaxf(v[rg * 4 + 2], 0.f) : 0.f;
        float e3 = g ? fmaxf(v[rg * 4 + 3], 0.f) : 0.f;
        if (EPI == 0) {
          uint2 u;
          u.x = (unsigned int)f2bf(e0) | ((unsigned int)f2bf(e1) << 16);
          u.y = (unsigned int)f2bf(e2) | ((unsigned int)f2bf(e3) << 16);
          short* dp = dstH + (size_t)img * PADIMG_ +
                      ((size_t)((r + 1) * 66 + (col + 1))) * 256 + ch;
          *(uint2*)dp = u;
        } else {
          size_t o = (size_t)img * IMG_ + (size_t)ch * HW_ + pidx;
          dstF[o] = xres[o] + e0;
          dstF[o + HW_] = xres[o + HW_] + e1;
          dstF[o + 2 * HW_] = xres[o + 2 * HW_] + e2;
          dstF[o + 3 * HW_] = xres[o + 3 * HW_] + e3;
        }
      }
    }
  }
}

// ---------------------------------------------------------------------------
extern "C" void kernel_launch(void* const* d_in, const int* in_sizes, int n_in,
                              void* d_out, int out_size, void* d_ws,
                              size_t ws_size, hipStream_t stream) {
  const float* x = (const float*)d_in[0];
  const float* w1 = (const float*)d_in[1];
  const float* w2 = (const float*)d_in[2];
  const float* wmask = (const float*)d_in[3];
  const float* bmask = (const float*)d_in[4];
  float* out = (float*)d_out;

  char* ws = (char*)d_ws;
  unsigned char* mask = (unsigned char*)ws;  // 64 KB
  short* Wt1 = (short*)(ws + 65536);         // 1.125 MiB
  short* Wt2 = Wt1 + WT_ELEMS_;              // 1.125 MiB
  const size_t fixed = 65536 + 4 * (size_t)WT_ELEMS_;  // mask + 2 Wt (bytes)
  short* Xp = (short*)(ws + fixed);

  const size_t tailpad = 32768;  // safety pad past last image
  const size_t per_img = 2 * (size_t)PADIMG_ * 2;  // Xp + Hp bytes per image
  int B = (ws_size > fixed + tailpad)
              ? (int)((ws_size - fixed - tailpad) / per_img) : 0;
  if (B > N_) B = N_;
  if (B < 1) B = 1;
  short* Hp = Xp + (size_t)B * PADIMG_;

  wt_kernel<<<dim3(256, 2), 256, 0, stream>>>(w1, w2, Wt1, Wt2);
  halo_zero<<<dim3(260, B, 2), 128, 0, stream>>>(Xp, Hp);

  for (int n0 = 0; n0 < N_; n0 += B) {
    const int nb = (N_ - n0 < B) ? (N_ - n0) : B;
    const int swz = (nb % 8 == 0) ? 1 : 0;
    xpadmask_kernel<<<dim3(64, nb), 256, 0, stream>>>(
        x + (size_t)n0 * IMG_, wmask, bmask, Xp, mask + n0 * HW_);
    conv_mfma<0><<<dim3(4, 8, nb), 512, 0, stream>>>(
        Xp, Wt1, mask + n0 * HW_, nullptr, Hp, nullptr, swz);
    conv_mfma<1><<<dim3(4, 8, nb), 512, 0, stream>>>(
        Hp, Wt2, mask + n0 * HW_, x + (size_t)n0 * IMG_, nullptr,
        out + (size_t)n0 * IMG_, swz);
  }
}

// Round 5
// 289.173 us; speedup vs baseline: 1.0879x; 1.0879x over previous
//
#include <hip/hip_runtime.h>
#include <hip/hip_bf16.h>

#define C_ 256
#define H_ 64
#define W_ 64
#define N_ 16
#define HW_ 4096
#define IMG_ (C_ * HW_)          // 1048576 elems (fp32 image)
#define PADIMG_ (66 * 66 * 256)  // 1115136 shorts per padded NHWC image
#define WT_ELEMS_ (9 * 16 * 256 * 16)

typedef short bf16x8 __attribute__((ext_vector_type(8)));
typedef float f32x16 __attribute__((ext_vector_type(16)));

__device__ __forceinline__ unsigned short f2bf(float f) {
  __hip_bfloat16 h = __float2bfloat16(f);  // RTNE
  return *reinterpret_cast<unsigned short*>(&h);
}

__device__ __forceinline__ void gld_lds16(const void* g, void* l) {
  __builtin_amdgcn_global_load_lds(
      (const __attribute__((address_space(1))) void*)g,
      (__attribute__((address_space(3))) void*)l, 16, 0, 0);
}

// ---------------------------------------------------------------------------
// Fused x->padded-NHWC-bf16 transform + mask logits (fp64, sign-exact).
// ---------------------------------------------------------------------------
__global__ __launch_bounds__(256) void xpadmask_kernel(
    const float* __restrict__ x, const float* __restrict__ wm,
    const float* __restrict__ bm, short* __restrict__ Xp,
    unsigned char* __restrict__ mask) {
  __shared__ unsigned short lds[64 * 260];
  __shared__ float wms[256];
  __shared__ double sums[4][64];
  const int h = blockIdx.x, img = blockIdx.y;
  const int tid = threadIdx.x;
  const int wv = tid >> 6, wl = tid & 63;
  wms[tid] = wm[tid];
  __syncthreads();
  const float* xi = x + (size_t)img * IMG_ + h * 64;
  double a0 = 0.0, a1 = 0.0, a2 = 0.0, a3 = 0.0;
#pragma unroll 4
  for (int i = 0; i < 16; ++i) {
#pragma unroll
    for (int u = 0; u < 4; ++u) {
      int c = (i * 4 + u) * 4 + wv;
      float v = xi[(size_t)c * HW_ + wl];
      lds[wl * 260 + c] = f2bf(v);
      double p = (double)v * (double)wms[c];
      if (u == 0) a0 += p;
      else if (u == 1) a1 += p;
      else if (u == 2) a2 += p;
      else a3 += p;
    }
  }
  sums[wv][wl] = (a0 + a1) + (a2 + a3);
  __syncthreads();
  short* Xpi = Xp + (size_t)img * PADIMG_ + ((h + 1) * 66 + 1) * 256;
#pragma unroll
  for (int j = 0; j < 16; ++j) {
    int w = j * 4 + wv;
    int c4 = wl * 4;
    uint2 d = *(const uint2*)&lds[w * 260 + c4];
    *(uint2*)&Xpi[(size_t)w * 256 + c4] = d;
  }
  if (wv == 0) {
    double t = sums[0][wl] + sums[1][wl] + sums[2][wl] + sums[3][wl] +
               (double)bm[0];
    mask[img * HW_ + h * 64 + wl] = (t > 0.0) ? 1 : 0;
  }
}

// ---------------------------------------------------------------------------
// Weight transform: Wt[t][kc][k][c16] = bf16(w[k][kc*16+c16][t])
// ---------------------------------------------------------------------------
__global__ __launch_bounds__(256) void wt_kernel(
    const float* __restrict__ w1, const float* __restrict__ w2,
    short* __restrict__ Wt1, short* __restrict__ Wt2) {
  const int k = blockIdx.x, c = threadIdx.x;
  const float* src = blockIdx.y ? w2 : w1;
  short* dst = blockIdx.y ? Wt2 : Wt1;
  const float* s = src + ((size_t)k * 256 + c) * 9;
  const int kc = c >> 4, ce = c & 15;
#pragma unroll
  for (int t = 0; t < 9; ++t)
    dst[(((size_t)t * 16 + kc) * 256 + k) * 16 + ce] = (short)f2bf(s[t]);
}

// ---------------------------------------------------------------------------
// Zero the padded halo (rows 0,65; cols 0,65) of Xp and Hp.
// ---------------------------------------------------------------------------
__global__ __launch_bounds__(128) void halo_zero(short* __restrict__ Xp,
                                                 short* __restrict__ Hp) {
  int p = blockIdx.x;  // 0..259 halo pixel id
  int r, c;
  if (p < 66) { r = 0; c = p; }
  else if (p < 132) { r = 65; c = p - 66; }
  else if (p < 196) { r = p - 131; c = 0; }
  else { r = p - 195; c = 65; }
  short* buf = blockIdx.z ? Hp : Xp;
  unsigned int* d = (unsigned int*)(buf + (size_t)blockIdx.y * PADIMG_ +
                                    (size_t)(r * 66 + c) * 256);
  d[threadIdx.x] = 0u;
}

// ---------------------------------------------------------------------------
// Implicit-GEMM 3x3 conv, v6 (4 waves/SIMD + W in LDS: no per-tap L2 dep).
// Round-4 lesson: 4 waves/SIMD alone didn't help because W stayed per-tap
// L2 loads (1-tap prefetch < L2 latency; lockstep waves all park on vmcnt;
// 8x-redundant W traffic). v6 removes global loads from the compute phase
// entirely: both B and W double-buffered in LDS, staged ONCE per block via
// global_load_lds at the TOP of kk (exactly 5 insts/wave, 40/block); the
// end-of-kk vmcnt(0) is ~free (stages issued a full compute phase earlier).
// Compute = pure {ds_read a/b (1-tap lookahead) + MFMA}; conflict-free.
// Block: 64 out-ch x 512 px (8 rows x 64 cols), 8 waves x 512 thr,
// wave w owns row h0+w; acc[2 ch][2 col] = 64 AGPR -> 4 waves/SIMD,
// 2 independent blocks/CU (de-correlated barriers).
// LDS 79104 B: B dbuf 2x21120 + W dbuf 2x18432 -> 2 blocks/CU exactly.
// Pipe ceilings /kk/CU: matrix 4.6K cyc, LDS-read 6.9K, L2 fetch ~57KB.
// EPI 0: dstH[padded NHWC] = g ? relu(acc) : 0  (g = 3x3 OR mask, fused dil)
// EPI 1: dstF[NCHW fp32]   = xres + (g ? relu(acc):0)  (g = std mask)
// ---------------------------------------------------------------------------
#define BBUF 10560   // shorts per B buffer (2 K-halves x 660 slots x 8)
#define WOFF 21120   // 2 * BBUF
#define WBUF 9216    // shorts per W buffer (9 taps x 2 ihalf x 64 ch x 8)

// Stage B(22 insts) + W(18 insts) for k-chunk kc into buffer buf.
// Wave w issues insts n = w, w+8, .., w+32 (exactly 5 each, vmcnt-symmetric).
__device__ __forceinline__ void stage_BW(short* sm, int buf, const short* Xb,
                                         const short* Wg, int ch0, int kc,
                                         int wave, int lane) {
  short* Bd = sm + buf * BBUF;
  short* Wd = sm + WOFF + buf * WBUF;
  const int ko = kc * 16;
#pragma unroll
  for (int q = 0; q < 5; ++q) {
    const int n = wave + 8 * q;
    if (n < 22) {
      // B inst: 11 per K-half; inst i<10 covers slots 64i..64i+63, inst 10
      // covers 596..659 (overlaps inst 9, identical bytes -> benign).
      const int h = (n >= 11) ? 1 : 0;
      const int i = n - h * 11;
      const int row0 = (i < 10) ? i * 64 : 596;
      gld_lds16(Xb + (size_t)(row0 + lane) * 256 + ko + h * 8,
                Bd + h * 5280 + row0 * 8);
    } else {
      // W inst m=n-22: t = m>>1, ihalf = m&1. 64 lanes cover 32 ch x 2 khalf:
      // lane l -> ch row ch0+ih*32+(l&31), k-half l>>5; LDS slot = lane.
      const int m = n - 22;
      const int t = m >> 1, ih = m & 1;
      gld_lds16(Wg + (((size_t)t * 16 + kc) * 256 + ch0 + ih * 32 +
                      (lane & 31)) * 16 + (lane >> 5) * 8,
                Wd + (t * 2 + ih) * 512);
    }
  }
}

template <int EPI>
__global__ __launch_bounds__(512, 4) void conv_mfma(
    const short* __restrict__ src, const short* __restrict__ Wt,
    const unsigned char* __restrict__ gate, const float* __restrict__ xres,
    short* __restrict__ dstH, float* __restrict__ dstF, int swz) {
  __shared__ __align__(16) short sm[2 * BBUF + 2 * WBUF];  // 79104 B

  const int tid = threadIdx.x;
  const int lane = tid & 63, wave = tid >> 6;  // 8 waves
  const int ln31 = lane & 31, kh = lane >> 5;

  // Block decode; swizzled path groups the 4 ch-sibling blocks on one XCD.
  int bx, by, bz;
  {
    int d = blockIdx.x + 4 * (blockIdx.y + 8 * blockIdx.z);
    if (swz) {
      int k = d & 7, j = d >> 3;
      bx = j & 3;
      by = (j >> 2) & 7;
      bz = ((j >> 5) << 3) + k;
    } else {
      bx = blockIdx.x;
      by = blockIdx.y;
      bz = blockIdx.z;
    }
  }
  const int ch0 = bx * 64;
  const int h0 = by * 8;
  const int img = bz;

  const short* Xb = src + (size_t)img * PADIMG_ + (size_t)(h0 * 66) * 256;

  f32x16 acc[2][2];
#pragma unroll
  for (int i = 0; i < 2; ++i)
#pragma unroll
    for (int j = 0; j < 2; ++j)
#pragma unroll
      for (int e = 0; e < 16; ++e) acc[i][j][e] = 0.f;

  // Prologue: stage k-chunk 0 into buf 0.
  stage_BW(sm, 0, Xb, Wt, ch0, 0, wave, lane);
  asm volatile("s_waitcnt vmcnt(0)\n\ts_barrier" ::: "memory");

  for (int kk = 0; kk < 16; ++kk) {
    const int cur = kk & 1;
    // Stage next k-chunk first: its latency hides under this kk's compute,
    // and the end-of-kk vmcnt(0) is then ~free.
    if (kk < 15) stage_BW(sm, cur ^ 1, Xb, Wt, ch0, kk + 1, wave, lane);

    // Per-thread read bases (compile-time offsets from here on).
    const short* Bth = sm + cur * BBUF + kh * 5280 + (wave * 66 + ln31) * 8;
    const short* Wth = sm + WOFF + cur * WBUF + (kh * 32 + ln31) * 8;

    bf16x8 ac[2], bc[2], an[2], bn[2];
#pragma unroll
    for (int i = 0; i < 2; ++i)  // tap 0 frags
      ac[i] = *(const bf16x8*)(Wth + (0 * 2 + i) * 512);
#pragma unroll
    for (int j = 0; j < 2; ++j)
      bc[j] = *(const bf16x8*)(Bth + (0 * 66 + j * 32 + 0) * 8);

#pragma unroll
    for (int t = 0; t < 9; ++t) {
      if (t < 8) {  // 1-tap lookahead (pure LDS, ~120cyc covered by MFMAs)
        const int dy = (t + 1) / 3, dx = (t + 1) % 3;
#pragma unroll
        for (int i = 0; i < 2; ++i)
          an[i] = *(const bf16x8*)(Wth + ((t + 1) * 2 + i) * 512);
#pragma unroll
        for (int j = 0; j < 2; ++j)
          bn[j] = *(const bf16x8*)(Bth + (dy * 66 + j * 32 + dx) * 8);
      }
      __builtin_amdgcn_s_setprio(1);
#pragma unroll
      for (int j = 0; j < 2; ++j) {
        acc[0][j] = __builtin_amdgcn_mfma_f32_32x32x16_bf16(ac[0], bc[j],
                                                            acc[0][j], 0, 0, 0);
        acc[1][j] = __builtin_amdgcn_mfma_f32_32x32x16_bf16(ac[1], bc[j],
                                                            acc[1][j], 0, 0, 0);
      }
      __builtin_amdgcn_s_setprio(0);
      if (t < 8) {
#pragma unroll
        for (int i = 0; i < 2; ++i) ac[i] = an[i];
#pragma unroll
        for (int j = 0; j < 2; ++j) bc[j] = bn[j];
      }
    }
    if (kk < 15)
      asm volatile("s_waitcnt vmcnt(0)\n\ts_barrier" ::: "memory");
  }

  // Epilogue. 32x32 D layout: col(pixel)=lane&31, row(ch)=(reg&3)+8*(reg>>2)
  // +4*(lane>>5)  => reg group rg gives 4 consecutive channels.
  const int r = h0 + wave;
#pragma unroll
  for (int j = 0; j < 2; ++j) {
    const int col = j * 32 + ln31;
    const int pidx = r * 64 + col;
    unsigned int g;
    if (EPI == 0) {
      // fused dilation: 3x3 OR of std mask around (r,col)
      g = 0;
#pragma unroll
      for (int dy = -1; dy <= 1; ++dy) {
        const int rr = r + dy;
        if (rr < 0 || rr >= H_) continue;
#pragma unroll
        for (int dx = -1; dx <= 1; ++dx) {
          const int cc = col + dx;
          if (cc < 0 || cc >= W_) continue;
          g |= gate[img * HW_ + rr * W_ + cc];
        }
      }
    } else {
      g = gate[img * HW_ + pidx];
    }
#pragma unroll
    for (int i = 0; i < 2; ++i) {
      const f32x16 v = acc[i][j];
#pragma unroll
      for (int rg = 0; rg < 4; ++rg) {
        const int ch = ch0 + i * 32 + rg * 8 + kh * 4;
        float e0 = g ? fmaxf(v[rg * 4 + 0], 0.f) : 0.f;
        float e1 = g ? fmaxf(v[rg * 4 + 1], 0.f) : 0.f;
        float e2 = g ? fmaxf(v[rg * 4 + 2], 0.f) : 0.f;
        float e3 = g ? fmaxf(v[rg * 4 + 3], 0.f) : 0.f;
        if (EPI == 0) {
          uint2 u;
          u.x = (unsigned int)f2bf(e0) | ((unsigned int)f2bf(e1) << 16);
          u.y = (unsigned int)f2bf(e2) | ((unsigned int)f2bf(e3) << 16);
          short* dp = dstH + (size_t)img * PADIMG_ +
                      ((size_t)((r + 1) * 66 + (col + 1))) * 256 + ch;
          *(uint2*)dp = u;
        } else {
          size_t o = (size_t)img * IMG_ + (size_t)ch * HW_ + pidx;
          dstF[o] = xres[o] + e0;
          dstF[o + HW_] = xres[o + HW_] + e1;
          dstF[o + 2 * HW_] = xres[o + 2 * HW_] + e2;
          dstF[o + 3 * HW_] = xres[o + 3 * HW_] + e3;
        }
      }
    }
  }
}

// ---------------------------------------------------------------------------
extern "C" void kernel_launch(void* const* d_in, const int* in_sizes, int n_in,
                              void* d_out, int out_size, void* d_ws,
                              size_t ws_size, hipStream_t stream) {
  const float* x = (const float*)d_in[0];
  const float* w1 = (const float*)d_in[1];
  const float* w2 = (const float*)d_in[2];
  const float* wmask = (const float*)d_in[3];
  const float* bmask = (const float*)d_in[4];
  float* out = (float*)d_out;

  char* ws = (char*)d_ws;
  unsigned char* mask = (unsigned char*)ws;  // 64 KB
  short* Wt1 = (short*)(ws + 65536);         // 1.125 MiB
  short* Wt2 = Wt1 + WT_ELEMS_;              // 1.125 MiB
  const size_t fixed = 65536 + 4 * (size_t)WT_ELEMS_;  // mask + 2 Wt (bytes)
  short* Xp = (short*)(ws + fixed);

  const size_t tailpad = 32768;  // safety pad past last image
  const size_t per_img = 2 * (size_t)PADIMG_ * 2;  // Xp + Hp bytes per image
  int B = (ws_size > fixed + tailpad)
              ? (int)((ws_size - fixed - tailpad) / per_img) : 0;
  if (B > N_) B = N_;
  if (B < 1) B = 1;
  short* Hp = Xp + (size_t)B * PADIMG_;

  wt_kernel<<<dim3(256, 2), 256, 0, stream>>>(w1, w2, Wt1, Wt2);
  halo_zero<<<dim3(260, B, 2), 128, 0, stream>>>(Xp, Hp);

  for (int n0 = 0; n0 < N_; n0 += B) {
    const int nb = (N_ - n0 < B) ? (N_ - n0) : B;
    const int swz = (nb % 8 == 0) ? 1 : 0;
    xpadmask_kernel<<<dim3(64, nb), 256, 0, stream>>>(
        x + (size_t)n0 * IMG_, wmask, bmask, Xp, mask + n0 * HW_);
    conv_mfma<0><<<dim3(4, 8, nb), 512, 0, stream>>>(
        Xp, Wt1, mask + n0 * HW_, nullptr, Hp, nullptr, swz);
    conv_mfma<1><<<dim3(4, 8, nb), 512, 0, stream>>>(
        Hp, Wt2, mask + n0 * HW_, x + (size_t)n0 * IMG_, nullptr,
        out + (size_t)n0 * IMG_, swz);
  }
}

// Round 7
// 288.482 us; speedup vs baseline: 1.0905x; 1.0024x over previous
//
#include <hip/hip_runtime.h>
#include <hip/hip_bf16.h>

#define C_ 256
#define H_ 64
#define W_ 64
#define N_ 16
#define HW_ 4096
#define IMG_ (C_ * HW_)          // 1048576 elems (fp32 image)
#define PADIMG_ (66 * 66 * 256)  // 1115136 shorts per padded NHWC image
#define WT_ELEMS_ (9 * 16 * 256 * 16)

typedef short bf16x8 __attribute__((ext_vector_type(8)));
typedef float f32x16 __attribute__((ext_vector_type(16)));

__device__ __forceinline__ unsigned short f2bf(float f) {
  __hip_bfloat16 h = __float2bfloat16(f);  // RTNE
  return *reinterpret_cast<unsigned short*>(&h);
}

__device__ __forceinline__ void gld_lds16(const void* g, void* l) {
  __builtin_amdgcn_global_load_lds(
      (const __attribute__((address_space(1))) void*)g,
      (__attribute__((address_space(3))) void*)l, 16, 0, 0);
}

// ---------------------------------------------------------------------------
// Fused x->padded-NHWC-bf16 transform + mask logits (fp64, sign-exact).
// Also zeroes this image's Xp halo (fused from halo_zero: row h+1 cols 0/65;
// blocks h==0 / h==63 zero the full padded rows 0 / 65). Regions are
// disjoint across blocks -> no race.
// ---------------------------------------------------------------------------
__global__ __launch_bounds__(256) void xpadmask_kernel(
    const float* __restrict__ x, const float* __restrict__ wm,
    const float* __restrict__ bm, short* __restrict__ Xp,
    unsigned char* __restrict__ mask) {
  __shared__ unsigned short lds[64 * 260];
  __shared__ float wms[256];
  __shared__ double sums[4][64];
  const int h = blockIdx.x, img = blockIdx.y;
  const int tid = threadIdx.x;
  const int wv = tid >> 6, wl = tid & 63;
  wms[tid] = wm[tid];
  __syncthreads();
  const float* xi = x + (size_t)img * IMG_ + h * 64;
  double a0 = 0.0, a1 = 0.0, a2 = 0.0, a3 = 0.0;
#pragma unroll 4
  for (int i = 0; i < 16; ++i) {
#pragma unroll
    for (int u = 0; u < 4; ++u) {
      int c = (i * 4 + u) * 4 + wv;
      float v = xi[(size_t)c * HW_ + wl];
      lds[wl * 260 + c] = f2bf(v);
      double p = (double)v * (double)wms[c];
      if (u == 0) a0 += p;
      else if (u == 1) a1 += p;
      else if (u == 2) a2 += p;
      else a3 += p;
    }
  }
  sums[wv][wl] = (a0 + a1) + (a2 + a3);
  __syncthreads();
  short* Xpimg = Xp + (size_t)img * PADIMG_;
  short* Xpi = Xpimg + ((h + 1) * 66 + 1) * 256;
#pragma unroll
  for (int j = 0; j < 16; ++j) {
    int w = j * 4 + wv;
    int c4 = wl * 4;
    uint2 d = *(const uint2*)&lds[w * 260 + c4];
    *(uint2*)&Xpi[(size_t)w * 256 + c4] = d;
  }
  // Xp halo: left/right columns of this padded row.
  if (tid < 128) {
    const int side = tid >> 6;    // 0 -> col 0, 1 -> col 65
    const int e = (tid & 63) * 4;
    *(uint2*)&Xpimg[((size_t)(h + 1) * 66 + side * 65) * 256 + e] =
        make_uint2(0u, 0u);
  }
  // Xp halo: full top/bottom padded rows.
  if (h == 0 || h == 63) {
    uint2* rowp = (uint2*)(Xpimg + (size_t)((h == 0) ? 0 : 65) * 66 * 256);
    for (int o = tid; o < 66 * 256 / 4; o += 256) rowp[o] = make_uint2(0u, 0u);
  }
  if (wv == 0) {
    double t = sums[0][wl] + sums[1][wl] + sums[2][wl] + sums[3][wl] +
               (double)bm[0];
    mask[img * HW_ + h * 64 + wl] = (t > 0.0) ? 1 : 0;
  }
}

// ---------------------------------------------------------------------------
// Weight transform: Wt[t][kc][k][c16] = bf16(w[k][kc*16+c16][t])
// ---------------------------------------------------------------------------
__global__ __launch_bounds__(256) void wt_kernel(
    const float* __restrict__ w1, const float* __restrict__ w2,
    short* __restrict__ Wt1, short* __restrict__ Wt2) {
  const int k = blockIdx.x, c = threadIdx.x;
  const float* src = blockIdx.y ? w2 : w1;
  short* dst = blockIdx.y ? Wt2 : Wt1;
  const float* s = src + ((size_t)k * 256 + c) * 9;
  const int kc = c >> 4, ce = c & 15;
#pragma unroll
  for (int t = 0; t < 9; ++t)
    dst[(((size_t)t * 16 + kc) * 256 + k) * 16 + ce] = (short)f2bf(s[t]);
}

// ---------------------------------------------------------------------------
// Zero the padded halo (rows 0,65; cols 0,65) of Hp (Xp handled in xpadmask).
// ---------------------------------------------------------------------------
__global__ __launch_bounds__(128) void halo_zero(short* __restrict__ Hp) {
  int p = blockIdx.x;  // 0..259 halo pixel id
  int r, c;
  if (p < 66) { r = 0; c = p; }
  else if (p < 132) { r = 65; c = p - 66; }
  else if (p < 196) { r = p - 131; c = 0; }
  else { r = p - 195; c = 65; }
  unsigned int* d = (unsigned int*)(Hp + (size_t)blockIdx.y * PADIMG_ +
                                    (size_t)(r * 66 + c) * 256);
  d[threadIdx.x] = 0u;
}

// ---------------------------------------------------------------------------
// Implicit-GEMM 3x3 conv, v7 (phase-clustered compute; round-6 rerun --
// round 6 failed at the infra level with no counters; diff audit found no
// deadlock/fault path, so resubmitting unchanged).
// v6 post-mortem: matrix pipe (4.65K cyc/kk/CU) and LDS-read pipe (~4.6-6.9K)
// are individually balanced but observed 10K cyc/kk -> the pipes barely
// overlap. Cause: per-kk barrier phase-locks all 8 waves of a block; ds and
// MFMA bursts alternate instead of overlapping; cross-block complementarity
// is unmanaged. v7 ports the 8-phase lesson at tap granularity:
//   - intra-kk phase barriers every 3 taps (t=3,6) cluster {12 ds_read |
//     12 MFMA} windows; the CU's 2 independent blocks interleave their
//     LDS-heavy and MFMA-heavy windows.
//   - setprio(1..0) per 3-tap MFMA cluster (T5; proven only with phase
//     structure, m218b).
//   - staging stays at kk top; single counted-free vmcnt(0) at kk end.
// Block: 64 out-ch x 512 px, 8 waves x 512 thr, wave = 64ch x 64px,
// acc[2][2] = 64 AGPR + 64 VGPR -> 4 waves/SIMD, 2 blocks/CU.
// LDS 79104 B: B dbuf 2x21120 + W dbuf 2x18432 shorts.
// EPI 0: dstH[padded NHWC] = g ? relu(acc) : 0  (g = 3x3 OR mask, fused dil)
// EPI 1: dstF[NCHW fp32]   = xres + (g ? relu(acc):0)  (g = std mask)
// ---------------------------------------------------------------------------
#define BBUF 10560   // shorts per B buffer (2 K-halves x 660 slots x 8)
#define WOFF 21120   // 2 * BBUF
#define WBUF 9216    // shorts per W buffer (9 taps x 2 ihalf x 64 ch x 8)

// Stage B(22 insts) + W(18 insts) for k-chunk kc into buffer buf.
// Wave w issues insts n = w, w+8, .., w+32 (exactly 5 each, vmcnt-symmetric).
__device__ __forceinline__ void stage_BW(short* sm, int buf, const short* Xb,
                                         const short* Wg, int ch0, int kc,
                                         int wave, int lane) {
  short* Bd = sm + buf * BBUF;
  short* Wd = sm + WOFF + buf * WBUF;
  const int ko = kc * 16;
#pragma unroll
  for (int q = 0; q < 5; ++q) {
    const int n = wave + 8 * q;
    if (n < 22) {
      // B inst: 11 per K-half; inst i<10 covers slots 64i..64i+63, inst 10
      // covers 596..659 (overlaps inst 9, identical bytes -> benign).
      const int h = (n >= 11) ? 1 : 0;
      const int i = n - h * 11;
      const int row0 = (i < 10) ? i * 64 : 596;
      gld_lds16(Xb + (size_t)(row0 + lane) * 256 + ko + h * 8,
                Bd + h * 5280 + row0 * 8);
    } else {
      // W inst m=n-22: t = m>>1, ihalf = m&1. 64 lanes cover 32 ch x 2 khalf.
      const int m = n - 22;
      const int t = m >> 1, ih = m & 1;
      gld_lds16(Wg + (((size_t)t * 16 + kc) * 256 + ch0 + ih * 32 +
                      (lane & 31)) * 16 + (lane >> 5) * 8,
                Wd + (t * 2 + ih) * 512);
    }
  }
}

template <int EPI>
__global__ __launch_bounds__(512, 4) void conv_mfma(
    const short* __restrict__ src, const short* __restrict__ Wt,
    const unsigned char* __restrict__ gate, const float* __restrict__ xres,
    short* __restrict__ dstH, float* __restrict__ dstF, int swz) {
  __shared__ __align__(16) short sm[2 * BBUF + 2 * WBUF];  // 79104 B

  const int tid = threadIdx.x;
  const int lane = tid & 63, wave = tid >> 6;  // 8 waves
  const int ln31 = lane & 31, kh = lane >> 5;

  // Block decode; swizzled path groups the 4 ch-sibling blocks on one XCD.
  int bx, by, bz;
  {
    int d = blockIdx.x + 4 * (blockIdx.y + 8 * blockIdx.z);
    if (swz) {
      int k = d & 7, j = d >> 3;
      bx = j & 3;
      by = (j >> 2) & 7;
      bz = ((j >> 5) << 3) + k;
    } else {
      bx = blockIdx.x;
      by = blockIdx.y;
      bz = blockIdx.z;
    }
  }
  const int ch0 = bx * 64;
  const int h0 = by * 8;
  const int img = bz;

  const short* Xb = src + (size_t)img * PADIMG_ + (size_t)(h0 * 66) * 256;

  f32x16 acc[2][2];
#pragma unroll
  for (int i = 0; i < 2; ++i)
#pragma unroll
    for (int j = 0; j < 2; ++j)
#pragma unroll
      for (int e = 0; e < 16; ++e) acc[i][j][e] = 0.f;

  // Prologue: stage k-chunk 0 into buf 0.
  stage_BW(sm, 0, Xb, Wt, ch0, 0, wave, lane);
  asm volatile("s_waitcnt vmcnt(0)\n\ts_barrier" ::: "memory");

  for (int kk = 0; kk < 16; ++kk) {
    const int cur = kk & 1;
    // Stage next k-chunk first: latency hides under this kk's compute.
    if (kk < 15) stage_BW(sm, cur ^ 1, Xb, Wt, ch0, kk + 1, wave, lane);

    // Per-thread read bases (compile-time offsets from here on).
    const short* Bth = sm + cur * BBUF + kh * 5280 + (wave * 66 + ln31) * 8;
    const short* Wth = sm + WOFF + cur * WBUF + (kh * 32 + ln31) * 8;

    bf16x8 ac[2], bc[2], an[2], bn[2];
#pragma unroll
    for (int i = 0; i < 2; ++i)  // tap 0 frags
      ac[i] = *(const bf16x8*)(Wth + (0 * 2 + i) * 512);
#pragma unroll
    for (int j = 0; j < 2; ++j)
      bc[j] = *(const bf16x8*)(Bth + (0 * 66 + j * 32 + 0) * 8);

#pragma unroll
    for (int t = 0; t < 9; ++t) {
      // Phase boundary every 3 taps: clusters {12 ds_read | 12 MFMA}
      // windows so the CU's 2 blocks interleave complementary pipes.
      // Uniform across all 8 waves (no divergence) -> no deadlock.
      if (t == 3 || t == 6) asm volatile("s_barrier" ::: "memory");
      if (t < 8) {  // 1-tap lookahead (pure LDS)
        const int dy = (t + 1) / 3, dx = (t + 1) % 3;
#pragma unroll
        for (int i = 0; i < 2; ++i)
          an[i] = *(const bf16x8*)(Wth + ((t + 1) * 2 + i) * 512);
#pragma unroll
        for (int j = 0; j < 2; ++j)
          bn[j] = *(const bf16x8*)(Bth + (dy * 66 + j * 32 + dx) * 8);
      }
      if (t % 3 == 0) __builtin_amdgcn_s_setprio(1);
#pragma unroll
      for (int j = 0; j < 2; ++j) {
        acc[0][j] = __builtin_amdgcn_mfma_f32_32x32x16_bf16(ac[0], bc[j],
                                                            acc[0][j], 0, 0, 0);
        acc[1][j] = __builtin_amdgcn_mfma_f32_32x32x16_bf16(ac[1], bc[j],
                                                            acc[1][j], 0, 0, 0);
      }
      if (t % 3 == 2) __builtin_amdgcn_s_setprio(0);
      if (t < 8) {
#pragma unroll
        for (int i = 0; i < 2; ++i) ac[i] = an[i];
#pragma unroll
        for (int j = 0; j < 2; ++j) bc[j] = bn[j];
      }
    }
    if (kk < 15)
      asm volatile("s_waitcnt vmcnt(0)\n\ts_barrier" ::: "memory");
  }

  // Epilogue. 32x32 D layout: col(pixel)=lane&31, row(ch)=(reg&3)+8*(reg>>2)
  // +4*(lane>>5)  => reg group rg gives 4 consecutive channels.
  const int r = h0 + wave;
#pragma unroll
  for (int j = 0; j < 2; ++j) {
    const int col = j * 32 + ln31;
    const int pidx = r * 64 + col;
    unsigned int g;
    if (EPI == 0) {
      // fused dilation: 3x3 OR of std mask around (r,col)
      g = 0;
#pragma unroll
      for (int dy = -1; dy <= 1; ++dy) {
        const int rr = r + dy;
        if (rr < 0 || rr >= H_) continue;
#pragma unroll
        for (int dx = -1; dx <= 1; ++dx) {
          const int cc = col + dx;
          if (cc < 0 || cc >= W_) continue;
          g |= gate[img * HW_ + rr * W_ + cc];
        }
      }
    } else {
      g = gate[img * HW_ + pidx];
    }
#pragma unroll
    for (int i = 0; i < 2; ++i) {
      const f32x16 v = acc[i][j];
#pragma unroll
      for (int rg = 0; rg < 4; ++rg) {
        const int ch = ch0 + i * 32 + rg * 8 + kh * 4;
        float e0 = g ? fmaxf(v[rg * 4 + 0], 0.f) : 0.f;
        float e1 = g ? fmaxf(v[rg * 4 + 1], 0.f) : 0.f;
        float e2 = g ? fmaxf(v[rg * 4 + 2], 0.f) : 0.f;
        float e3 = g ? fmaxf(v[rg * 4 + 3], 0.f) : 0.f;
        if (EPI == 0) {
          uint2 u;
          u.x = (unsigned int)f2bf(e0) | ((unsigned int)f2bf(e1) << 16);
          u.y = (unsigned int)f2bf(e2) | ((unsigned int)f2bf(e3) << 16);
          short* dp = dstH + (size_t)img * PADIMG_ +
                      ((size_t)((r + 1) * 66 + (col + 1))) * 256 + ch;
          *(uint2*)dp = u;
        } else {
          size_t o = (size_t)img * IMG_ + (size_t)ch * HW_ + pidx;
          dstF[o] = xres[o] + e0;
          dstF[o + HW_] = xres[o + HW_] + e1;
          dstF[o + 2 * HW_] = xres[o + 2 * HW_] + e2;
          dstF[o + 3 * HW_] = xres[o + 3 * HW_] + e3;
        }
      }
    }
  }
}

// ---------------------------------------------------------------------------
extern "C" void kernel_launch(void* const* d_in, const int* in_sizes, int n_in,
                              void* d_out, int out_size, void* d_ws,
                              size_t ws_size, hipStream_t stream) {
  const float* x = (const float*)d_in[0];
  const float* w1 = (const float*)d_in[1];
  const float* w2 = (const float*)d_in[2];
  const float* wmask = (const float*)d_in[3];
  const float* bmask = (const float*)d_in[4];
  float* out = (float*)d_out;

  char* ws = (char*)d_ws;
  unsigned char* mask = (unsigned char*)ws;  // 64 KB
  short* Wt1 = (short*)(ws + 65536);         // 1.125 MiB
  short* Wt2 = Wt1 + WT_ELEMS_;              // 1.125 MiB
  const size_t fixed = 65536 + 4 * (size_t)WT_ELEMS_;  // mask + 2 Wt (bytes)
  short* Xp = (short*)(ws + fixed);

  const size_t tailpad = 32768;  // safety pad past last image
  const size_t per_img = 2 * (size_t)PADIMG_ * 2;  // Xp + Hp bytes per image
  int B = (ws_size > fixed + tailpad)
              ? (int)((ws_size - fixed - tailpad) / per_img) : 0;
  if (B > N_) B = N_;
  if (B < 1) B = 1;
  short* Hp = Xp + (size_t)B * PADIMG_;

  wt_kernel<<<dim3(256, 2), 256, 0, stream>>>(w1, w2, Wt1, Wt2);
  halo_zero<<<dim3(260, B), 128, 0, stream>>>(Hp);

  for (int n0 = 0; n0 < N_; n0 += B) {
    const int nb = (N_ - n0 < B) ? (N_ - n0) : B;
    const int swz = (nb % 8 == 0) ? 1 : 0;
    xpadmask_kernel<<<dim3(64, nb), 256, 0, stream>>>(
        x + (size_t)n0 * IMG_, wmask, bmask, Xp, mask + n0 * HW_);
    conv_mfma<0><<<dim3(4, 8, nb), 512, 0, stream>>>(
        Xp, Wt1, mask + n0 * HW_, nullptr, Hp, nullptr, swz);
    conv_mfma<1><<<dim3(4, 8, nb), 512, 0, stream>>>(
        Hp, Wt2, mask + n0 * HW_, x + (size_t)n0 * IMG_, nullptr,
        out + (size_t)n0 * IMG_, swz);
  }
}